// Round 3
// baseline (1468.002 us; speedup 1.0000x reference)
//
#include <hip/hip_runtime.h>
#include <hip/hip_bf16.h>

// B=32, C=64, N=4096, K=N/2+1=2049, modes=64
constexpr int NSEQ  = 4096;   // first transform length
constexpr int MROWS = 2049;   // cas rows actually needed (= K)
constexpr int MPAD  = 2176;   // 17 * 128 row tiles
constexpr int COLS  = 4096;   // [y | y_flip] columns = 2*B*C
constexpr int KHT   = 2049;   // second transform length
constexpr int TABST = 2080;   // padded row stride of casK table
constexpr int BATCH = 32;

// fp32(2*pi) = 0x40C90FDB -- must match the reference's fp32 arg chain
constexpr float TPI = 6.283185307179586f;

// workspace layout (float offsets); total ~73 MB
constexpr size_t A_OFF   = 0;                         // cas_N [MPAD][NSEQ]
constexpr size_t A_SZ    = (size_t)MPAD * NSEQ;
constexpr size_t C_OFF   = A_OFF + A_SZ;              // C = cas @ [y|yf]  [MPAD][COLS]
constexpr size_t C_SZ    = (size_t)MPAD * COLS;
constexpr size_t TAB_OFF = C_OFF + C_SZ;              // casK table [128][TABST]
constexpr size_t TAB_SZ  = (size_t)128 * TABST;
constexpr size_t OH_OFF  = TAB_OFF + TAB_SZ;          // out_ht [32][64][64]

// ---------------- prep: cas_N table, fp32-faithful to the reference ----------
__global__ __launch_bounds__(256) void prep_A(float* __restrict__ A) {
  int idx = blockIdx.x * 256 + threadIdx.x;
  if (idx >= MPAD * NSEQ) return;
  int n = idx >> 12;          // row = output frequency (first einsum index)
  int p = idx & (NSEQ - 1);
  float v = 0.0f;
  if (n < MROWS) {
    float t1  = TPI * (float)n;          // fl32(2pi * n)   (row index first!)
    float t2  = t1 * (float)p;           // fl32(t1 * p)
    float arg = t2 * (1.0f / 4096.0f);   // exact (pow2), same as /N
    v = cosf(arg) + sinf(arg);
  }
  A[idx] = v;
}

// ---------------- prep: cas_K sparse-column table, 1/K folded in -------------
__global__ __launch_bounds__(256) void prep_tab(float* __restrict__ tab) {
  int idx = blockIdx.x * 256 + threadIdx.x;
  if (idx >= 128 * TABST) return;
  int j  = idx / TABST;
  int np = idx - j * TABST;
  float v = 0.0f;
  if (np < KHT) {
    int c = j >> 1, b = j & 1;
    int pp = 32 * c + b;                 // the only cas_K columns ever used
    float t1  = TPI * (float)np;
    float t2  = t1 * (float)pp;
    float arg = t2 / 2049.0f;            // IEEE fp32 divide, like reference
    v = (cosf(arg) + sinf(arg)) * (1.0f / 2049.0f);
  }
  tab[idx] = v;
}

// ---------------- big GEMM: C[n][col] = cas_N @ [y | y_flip] -----------------
// y[d,p,m]      = x[d*262144 + p*64 + m]                      (pure reinterpret)
// y_flip[d,p,m] = x[d*262144 + (j2 & ~4095) + 4095 - (j2&4095)], j2 = p*64+m
__global__ __launch_bounds__(256) void gemm_cas(const float* __restrict__ A,
                                                const float* __restrict__ x,
                                                float* __restrict__ Cm) {
  __shared__ __align__(16) float As[16][132];
  __shared__ __align__(16) float Bs[16][132];
  const int t  = threadIdx.x;
  const int bm = blockIdx.y * 128;
  const int bc = blockIdx.x * 128;
  const int ti = t >> 4;
  const int tj = t & 15;
  const bool flip = (bc >= 2048);        // uniform per block (2048 % 128 == 0)

  float acc[8][8] = {};

  for (int k0 = 0; k0 < NSEQ; k0 += 16) {
    #pragma unroll
    for (int e = 0; e < 8; ++e) {        // stage A [16k][128r]
      int idx = t + e * 256;
      int kk = idx & 15;
      int r  = idx >> 4;
      As[kk][r] = A[(bm + r) * NSEQ + k0 + kk];
    }
    #pragma unroll
    for (int e = 0; e < 8; ++e) {        // stage B [16k][128c], gathered from x
      int idx = t + e * 256;
      int j  = idx & 127;
      int kk = idx >> 7;
      int p  = k0 + kk;
      int cg = bc + j - (flip ? 2048 : 0);
      int d  = cg >> 6;
      int m  = cg & 63;
      int j2 = p * 64 + m;
      int off = flip ? ((j2 & ~4095) + 4095 - (j2 & 4095)) : j2;
      Bs[kk][j] = x[d * 262144 + off];
    }
    __syncthreads();
    for (int k = 0; k < 16; ++k) {
      float a[8], b[8];
      *(float4*)&a[0] = *(const float4*)&As[k][ti * 8];
      *(float4*)&a[4] = *(const float4*)&As[k][ti * 8 + 4];
      *(float4*)&b[0] = *(const float4*)&Bs[k][tj * 8];
      *(float4*)&b[4] = *(const float4*)&Bs[k][tj * 8 + 4];
      #pragma unroll
      for (int ii = 0; ii < 8; ++ii)
        #pragma unroll
        for (int jj = 0; jj < 8; ++jj)
          acc[ii][jj] += a[ii] * b[jj];
    }
    __syncthreads();
  }

  #pragma unroll
  for (int ii = 0; ii < 8; ++ii) {
    int r = bm + ti * 8 + ii;
    float* cp = Cm + (size_t)r * COLS + bc + tj * 8;
    *(float4*)cp       = make_float4(acc[ii][0], acc[ii][1], acc[ii][2], acc[ii][3]);
    *(float4*)(cp + 4) = make_float4(acc[ii][4], acc[ii][5], acc[ii][6], acc[ii][7]);
  }
}

// ---------------- compl_mul: out_ht[b,o,m], modes=64 -------------------------
// x1[b,i,m] = x_ht[b,i,m] = C[m][b*64+i];  neg index mn = (64-m)&63
__global__ __launch_bounds__(256) void complmul(const float* __restrict__ Cm,
                                                const float* __restrict__ W,
                                                float* __restrict__ oh) {
  __shared__ float cl[64 * 65];
  const int t  = threadIdx.x;
  const int bq = blockIdx.y;             // batch
  const int og = blockIdx.x;             // o-group (4 o's per block)
  #pragma unroll
  for (int e = 0; e < 16; ++e) {         // stage C rows 0..63, cols bq*64..+64
    int idx = t + e * 256;
    int i = idx & 63, m = idx >> 6;
    cl[m * 65 + i] = Cm[(size_t)m * COLS + bq * 64 + i];
  }
  __syncthreads();
  const int m  = t & 63;
  const int o  = og * 4 + (t >> 6);
  const int mn = (64 - m) & 63;
  float s = 0.0f;
  for (int i = 0; i < 64; ++i) {
    float w  = W[i * 4096 + o * 64 + m];
    float wn = W[i * 4096 + o * 64 + mn];
    s += cl[m * 65 + i] * (w + wn) + cl[mn * 65 + i] * (w - wn);
  }
  oh[bq * 4096 + o * 64 + m] = 0.5f * s;
}

// ---------------- final: xi (sparse 64-term) * cos(atan2) --------------------
__global__ __launch_bounds__(256) void final_k(const float* __restrict__ Cm,
                                               const float* __restrict__ tab,
                                               const float* __restrict__ oh,
                                               float* __restrict__ out) {
  __shared__ float tl[128 * 32];
  __shared__ float ol[64 * 64];
  const int t  = threadIdx.x;
  const int d  = blockIdx.y;
  const int n0 = blockIdx.x * 32;
  #pragma unroll
  for (int e = 0; e < 16; ++e) {         // stage casK table slab [128][32]
    int idx = t + e * 256;
    tl[idx] = tab[(idx >> 5) * TABST + n0 + (idx & 31)];
  }
  #pragma unroll
  for (int e = 0; e < 16; ++e) {         // stage out_ht[d]
    int idx = t + e * 256;
    ol[idx] = oh[d * 4096 + idx];
  }
  __syncthreads();
  const int mp   = t & 63;
  const int nsub = t >> 6;

  float ohreg[64];                       // gather once, reuse for all 8 n'
  #pragma unroll
  for (int c = 0; c < 64; ++c)
    ohreg[c] = ol[c * 64 + ((mp - c) & 63)];

  float acc[8] = {};
  #pragma unroll
  for (int c = 0; c < 64; ++c) {
    const float* tp = &tl[(2 * c + (c > mp ? 1 : 0)) * 32 + nsub * 8];
    float tv[8];
    *(float4*)&tv[0] = *(const float4*)tp;
    *(float4*)&tv[4] = *(const float4*)(tp + 4);
    #pragma unroll
    for (int q = 0; q < 8; ++q) acc[q] += tv[q] * ohreg[c];
  }
  #pragma unroll
  for (int q = 0; q < 8; ++q) {
    int np = n0 + nsub * 8 + q;
    if (np < KHT) {
      float av = Cm[(size_t)np * COLS + d * 64 + mp];          // x_ht
      float bv = Cm[(size_t)np * COLS + 2048 + d * 64 + mp];   // x_ht_flip
      float r2 = av * av + bv * bv;
      float cosp = (r2 > 0.0f) ? av / sqrtf(r2) : 1.0f;        // cos(atan2(bv,av))
      out[d * 131136 + mp * 2049 + np] = acc[q] * cosp;        // 131136 = 64*2049
    }
  }
}

extern "C" void kernel_launch(void* const* d_in, const int* in_sizes, int n_in,
                              void* d_out, int out_size, void* d_ws, size_t ws_size,
                              hipStream_t stream) {
  const float* x = (const float*)d_in[0];     // (32, 64, 4096) f32
  const float* W = (const float*)d_in[1];     // (64, 64, 64) f32
  float* out = (float*)d_out;                 // (32, 64, 2049) f32
  float* ws  = (float*)d_ws;                  // needs ~73 MB
  float* A   = ws + A_OFF;
  float* Cm  = ws + C_OFF;
  float* tab = ws + TAB_OFF;
  float* oh  = ws + OH_OFF;

  prep_A  <<<dim3((MPAD * NSEQ) / 256), dim3(256), 0, stream>>>(A);
  prep_tab<<<dim3((128 * TABST + 255) / 256), dim3(256), 0, stream>>>(tab);
  gemm_cas<<<dim3(COLS / 128, MPAD / 128), dim3(256), 0, stream>>>(A, x, Cm);
  complmul<<<dim3(16, BATCH), dim3(256), 0, stream>>>(Cm, W, oh);
  final_k <<<dim3((KHT + 31) / 32, BATCH), dim3(256), 0, stream>>>(Cm, tab, oh, out);
}

// Round 4
// 878.647 us; speedup vs baseline: 1.6708x; 1.6708x over previous
//
#include <hip/hip_runtime.h>
#include <hip/hip_bf16.h>

typedef __attribute__((ext_vector_type(8))) short short8;
typedef __attribute__((ext_vector_type(4))) float f32x4;

// B=32, C=64, N=4096, K=2049, modes=64
constexpr int NSEQ  = 4096;
constexpr int MROWS = 2049;
constexpr int MPAD  = 2176;   // 17 * 128
constexpr int KHT   = 2049;
constexpr int TABST = 2080;
constexpr int BATCH = 32;
constexpr int SLABS = 512;    // 4096 / 8
constexpr float TPI = 6.283185307179586f;   // fp32(2*pi), matches reference chain

constexpr size_t PLANE_USH = (size_t)SLABS * MPAD * 8;     // 8,912,896 shorts/plane

// ws layout in float units (total ~73.4 MB)
constexpr size_t ASPL_FLT = 3 * PLANE_USH / 2;             // 13,369,344
constexpr size_t COSP_OFF = ASPL_FLT;
constexpr size_t COSP_SZ  = (size_t)MPAD * 2048;           // 4,456,448
constexpr size_t XH_OFF   = COSP_OFF + COSP_SZ;
constexpr size_t XH_SZ    = (size_t)64 * 2048;
constexpr size_t TAB_OFF  = XH_OFF + XH_SZ;
constexpr size_t TAB_SZ   = (size_t)128 * TABST;
constexpr size_t OH_OFF   = TAB_OFF + TAB_SZ;

// ---- 3-way bf16 split: v = f(h0)+f(h1)+f(h2) + O(2^-27 |v|) ----------------
__device__ __forceinline__ void split3(float v, short &h0, short &h1, short &h2) {
  __hip_bfloat16 b0 = __float2bfloat16(v);
  float f0 = __bfloat162float(b0);
  float r1 = v - f0;                       // exact (Sterbenz)
  __hip_bfloat16 b1 = __float2bfloat16(r1);
  float f1 = __bfloat162float(b1);
  float r2 = r1 - f1;                      // exact
  __hip_bfloat16 b2 = __float2bfloat16(r2);
  h0 = __builtin_bit_cast(short, b0);
  h1 = __builtin_bit_cast(short, b1);
  h2 = __builtin_bit_cast(short, b2);
}

__device__ __forceinline__ void gl_lds16(const short* g, short* s) {
  __builtin_amdgcn_global_load_lds((const __attribute__((address_space(1))) void*)g,
                                   (__attribute__((address_space(3))) void*)s, 16, 0, 0);
}

// ---------------- prep: cas_N split planes, slab-major [k/8][row][8] --------
__global__ __launch_bounds__(256) void prep_A(short* __restrict__ Aq) {
  int row = blockIdx.x * 256 + threadIdx.x;
  if (row >= MPAD) return;
  int slab = blockIdx.y;
  short8 o0, o1, o2;
  float t1 = TPI * (float)row;             // fl32(2pi*n), n = row first!
  #pragma unroll
  for (int e = 0; e < 8; ++e) {
    float v = 0.0f;
    if (row < MROWS) {
      float t2  = t1 * (float)(slab * 8 + e);   // fl32(t1*p)
      float arg = t2 * (1.0f / 4096.0f);        // exact pow2 divide
      v = cosf(arg) + sinf(arg);
    }
    short h0, h1, h2; split3(v, h0, h1, h2);
    o0[e] = h0; o1[e] = h1; o2[e] = h2;
  }
  size_t base = (size_t)slab * (MPAD * 8) + (size_t)row * 8;
  *(short8*)(Aq + base)                  = o0;
  *(short8*)(Aq + PLANE_USH + base)      = o1;
  *(short8*)(Aq + 2 * PLANE_USH + base)  = o2;
}

// ---------------- prep: cas_K sparse-column table, 1/K folded in ------------
__global__ __launch_bounds__(256) void prep_tab(float* __restrict__ tab) {
  int idx = blockIdx.x * 256 + threadIdx.x;
  if (idx >= 128 * TABST) return;
  int j  = idx / TABST;
  int np = idx - j * TABST;
  float v = 0.0f;
  if (np < KHT) {
    int c = j >> 1, b = j & 1;
    int pp = 32 * c + b;
    float t1  = TPI * (float)np;
    float t2  = t1 * (float)pp;
    float arg = t2 / 2049.0f;
    v = (cosf(arg) + sinf(arg)) * (1.0f / 2049.0f);
  }
  tab[idx] = v;
}

// ---------------- MFMA GEMM + fused cos(atan2) epilogue ---------------------
// Block: rows bm..bm+127 (n), cols c0..c0+63 (c), block-col j: c=c0+(j>>1),
// variant j&1 (0=normal x_ht "a", 1=flipped "b"). 6-product bf16 fp32-emulation.
__global__ __launch_bounds__(256, 2) void gemm_mfma(const short* __restrict__ Aq,
                                                    const float* __restrict__ x,
                                                    float* __restrict__ cosp,
                                                    float* __restrict__ xh64) {
  __shared__ __align__(16) short As[3][4096];   // [plane][slab*1024 + row*8 + e]
  __shared__ __align__(16) short Bs[3][4096];   // [plane][slab*1024 + j*8 + e]
  const int t    = threadIdx.x;
  const int lane = t & 63;
  const int w    = t >> 6;
  const int wr   = w >> 1, wc = w & 1;
  const int bm   = blockIdx.y * 128;
  const int c0   = blockIdx.x * 64;

  // B staging constants (2 tasks/thread, same j)
  const int j    = t & 127;
  const int sA   = t >> 7;                 // slabs sA and sA+2
  const int cc   = c0 + (j >> 1);
  const int flip = j & 1;
  const int mm   = cc & 63;
  const float* xb = x + (cc >> 6) * 262144;
  const int bi0  = (sA * 128 + j) * 8;
  const int bi1  = ((sA + 2) * 128 + j) * 8;

  int aIdx[4], bIdx[4];
  #pragma unroll
  for (int f = 0; f < 4; ++f) {
    aIdx[f] = (lane >> 4) * 1024 + (wr * 64 + f * 16 + (lane & 15)) * 8;
    bIdx[f] = (lane >> 4) * 1024 + (wc * 64 + f * 16 + (lane & 15)) * 8;
  }

  f32x4 accM[4][4] = {};   // a0*b0 only (large partial sums)
  f32x4 accL[4][4] = {};   // the 5 small products (partials ~0.3 -> tiny ulp)

  for (int k0 = 0; k0 < NSEQ; k0 += 32) {
    // ---- stage A: 24 chunks of 1 KiB via global_load_lds, 6 per wave ----
    const int sg0 = k0 >> 3;
    #pragma unroll
    for (int i = 0; i < 6; ++i) {
      int q = w * 6 + i;                   // q = p*8 + s*2 + h
      int p = q >> 3, s = (q >> 1) & 3, h = q & 1;
      const short* gp = Aq + (size_t)p * PLANE_USH + (size_t)(sg0 + s) * (MPAD * 8)
                        + (size_t)(bm + h * 64 + lane) * 8;
      gl_lds16(gp, &As[p][s * 1024 + h * 512]);
    }
    // ---- stage B: gather fp32 from x, split3, ds_write_b128 x3 ----
    #pragma unroll
    for (int tk = 0; tk < 2; ++tk) {
      int s  = (tk == 0) ? sA : sA + 2;
      int kb = k0 + s * 8;
      int hi = (kb >> 6) << 12;
      int lo = ((kb & 63) << 6) + mm;
      int base = flip ? (hi + 4095 - lo) : (hi + lo);
      int step = flip ? -64 : 64;
      short8 p0, p1, p2;
      #pragma unroll
      for (int e = 0; e < 8; ++e) {
        float v = xb[base + e * step];
        short h0, h1, h2; split3(v, h0, h1, h2);
        p0[e] = h0; p1[e] = h1; p2[e] = h2;
      }
      int bi = (tk == 0) ? bi0 : bi1;
      *(short8*)&Bs[0][bi] = p0;
      *(short8*)&Bs[1][bi] = p1;
      *(short8*)&Bs[2][bi] = p2;
    }
    __syncthreads();

    // ---- compute: 96 MFMA / wave ----
    short8 fa0[4], fa1[4], fa2[4];
    #pragma unroll
    for (int f = 0; f < 4; ++f) {
      fa0[f] = *(const short8*)&As[0][aIdx[f]];
      fa1[f] = *(const short8*)&As[1][aIdx[f]];
      fa2[f] = *(const short8*)&As[2][aIdx[f]];
    }
    {
      short8 fb[4];
      #pragma unroll
      for (int f = 0; f < 4; ++f) fb[f] = *(const short8*)&Bs[0][bIdx[f]];
      #pragma unroll
      for (int fi = 0; fi < 4; ++fi)
        #pragma unroll
        for (int fj = 0; fj < 4; ++fj) {
          accM[fi][fj] = __builtin_amdgcn_mfma_f32_16x16x32_bf16(fa0[fi], fb[fj], accM[fi][fj], 0, 0, 0);
          accL[fi][fj] = __builtin_amdgcn_mfma_f32_16x16x32_bf16(fa1[fi], fb[fj], accL[fi][fj], 0, 0, 0);
          accL[fi][fj] = __builtin_amdgcn_mfma_f32_16x16x32_bf16(fa2[fi], fb[fj], accL[fi][fj], 0, 0, 0);
        }
    }
    {
      short8 fb[4];
      #pragma unroll
      for (int f = 0; f < 4; ++f) fb[f] = *(const short8*)&Bs[1][bIdx[f]];
      #pragma unroll
      for (int fi = 0; fi < 4; ++fi)
        #pragma unroll
        for (int fj = 0; fj < 4; ++fj) {
          accL[fi][fj] = __builtin_amdgcn_mfma_f32_16x16x32_bf16(fa0[fi], fb[fj], accL[fi][fj], 0, 0, 0);
          accL[fi][fj] = __builtin_amdgcn_mfma_f32_16x16x32_bf16(fa1[fi], fb[fj], accL[fi][fj], 0, 0, 0);
        }
    }
    {
      short8 fb[4];
      #pragma unroll
      for (int f = 0; f < 4; ++f) fb[f] = *(const short8*)&Bs[2][bIdx[f]];
      #pragma unroll
      for (int fi = 0; fi < 4; ++fi)
        #pragma unroll
        for (int fj = 0; fj < 4; ++fj)
          accL[fi][fj] = __builtin_amdgcn_mfma_f32_16x16x32_bf16(fa0[fi], fb[fj], accL[fi][fj], 0, 0, 0);
    }
    __syncthreads();
  }

  // ---- epilogue: pair a (even j) with b (odd j) via lane-xor-1, fuse cosp ----
  #pragma unroll
  for (int fi = 0; fi < 4; ++fi) {
    int row0 = bm + wr * 64 + fi * 16 + ((lane >> 4) << 2);
    #pragma unroll
    for (int fj = 0; fj < 4; ++fj) {
      int jc = wc * 64 + fj * 16 + (lane & 15);
      int c  = c0 + (jc >> 1);
      #pragma unroll
      for (int r = 0; r < 4; ++r) {
        float v = accM[fi][fj][r] + accL[fi][fj][r];
        float o = __shfl_xor(v, 1, 64);
        float a = (lane & 1) ? o : v;
        float b = (lane & 1) ? v : o;
        float r2 = a * a + b * b;
        float cp = (r2 > 0.0f) ? (a / sqrtf(r2)) : 1.0f;   // cos(atan2(b,a))
        if ((lane & 1) == 0) {
          cosp[(size_t)(row0 + r) * 2048 + c] = cp;
          if (bm == 0 && wr == 0) xh64[(row0 + r) * 2048 + c] = a;  // rows 0..63
        }
      }
    }
  }
}

// ---------------- compl_mul: out_ht[b,o,m], modes=64 ------------------------
__global__ __launch_bounds__(256) void complmul(const float* __restrict__ xh64,
                                                const float* __restrict__ W,
                                                float* __restrict__ oh) {
  __shared__ float cl[64 * 65];
  const int t  = threadIdx.x;
  const int bq = blockIdx.y;
  const int og = blockIdx.x;
  #pragma unroll
  for (int e = 0; e < 16; ++e) {
    int idx = t + e * 256;
    int i = idx & 63, m = idx >> 6;
    cl[m * 65 + i] = xh64[m * 2048 + bq * 64 + i];
  }
  __syncthreads();
  const int m  = t & 63;
  const int o  = og * 4 + (t >> 6);
  const int mn = (64 - m) & 63;
  float s = 0.0f;
  for (int i = 0; i < 64; ++i) {
    float w  = W[i * 4096 + o * 64 + m];
    float wn = W[i * 4096 + o * 64 + mn];
    s += cl[m * 65 + i] * (w + wn) + cl[mn * 65 + i] * (w - wn);
  }
  oh[bq * 4096 + o * 64 + m] = 0.5f * s;
}

// ---------------- final: xi (sparse 64-term) * cosp -------------------------
__global__ __launch_bounds__(256) void final_k(const float* __restrict__ cosp,
                                               const float* __restrict__ tab,
                                               const float* __restrict__ oh,
                                               float* __restrict__ out) {
  __shared__ float tl[128 * 32];
  __shared__ float ol[64 * 64];
  const int t  = threadIdx.x;
  const int d  = blockIdx.y;
  const int n0 = blockIdx.x * 32;
  #pragma unroll
  for (int e = 0; e < 16; ++e) {
    int idx = t + e * 256;
    tl[idx] = tab[(idx >> 5) * TABST + n0 + (idx & 31)];
  }
  #pragma unroll
  for (int e = 0; e < 16; ++e) {
    int idx = t + e * 256;
    ol[idx] = oh[d * 4096 + idx];
  }
  __syncthreads();
  const int mp   = t & 63;
  const int nsub = t >> 6;

  float ohreg[64];
  #pragma unroll
  for (int c = 0; c < 64; ++c)
    ohreg[c] = ol[c * 64 + ((mp - c) & 63)];

  float acc[8] = {};
  #pragma unroll
  for (int c = 0; c < 64; ++c) {
    const float* tp = &tl[(2 * c + (c > mp ? 1 : 0)) * 32 + nsub * 8];
    float tv[8];
    *(float4*)&tv[0] = *(const float4*)tp;
    *(float4*)&tv[4] = *(const float4*)(tp + 4);
    #pragma unroll
    for (int q = 0; q < 8; ++q) acc[q] += tv[q] * ohreg[c];
  }
  #pragma unroll
  for (int q = 0; q < 8; ++q) {
    int np = n0 + nsub * 8 + q;
    if (np < KHT) {
      float cp = cosp[(size_t)np * 2048 + d * 64 + mp];
      out[d * 131136 + mp * 2049 + np] = acc[q] * cp;
    }
  }
}

extern "C" void kernel_launch(void* const* d_in, const int* in_sizes, int n_in,
                              void* d_out, int out_size, void* d_ws, size_t ws_size,
                              hipStream_t stream) {
  const float* x = (const float*)d_in[0];     // (32, 64, 4096) f32
  const float* W = (const float*)d_in[1];     // (64, 64, 64) f32
  float* out = (float*)d_out;                 // (32, 64, 2049) f32
  float* ws  = (float*)d_ws;

  short* Aq    = (short*)ws;
  float* cospB = ws + COSP_OFF;
  float* xh64  = ws + XH_OFF;
  float* tab   = ws + TAB_OFF;
  float* oh    = ws + OH_OFF;

  prep_A   <<<dim3((MPAD + 255) / 256, SLABS), dim3(256), 0, stream>>>(Aq);
  prep_tab <<<dim3((128 * TABST + 255) / 256), dim3(256), 0, stream>>>(tab);
  gemm_mfma<<<dim3(32, 17), dim3(256), 0, stream>>>(Aq, x, cospB, xh64);
  complmul <<<dim3(16, BATCH), dim3(256), 0, stream>>>(xh64, W, oh);
  final_k  <<<dim3(65, BATCH), dim3(256), 0, stream>>>(cospB, tab, oh, out);
}